// Round 4
// baseline (732.428 us; speedup 1.0000x reference)
//
#include <hip/hip_runtime.h>

#define NN 20000
#define EE 320000
#define EF 340000   /* EE + NN self loops */
#define EDIM 22

typedef short bf16x8 __attribute__((ext_vector_type(8)));
typedef float f32x4 __attribute__((ext_vector_type(4)));

__device__ __forceinline__ float b2f(ushort u) {
  union { unsigned u; float f; } v;
  v.u = ((unsigned)u) << 16;
  return v.f;
}
__device__ __forceinline__ ushort f2b(float f) {
  union { float f; unsigned u; } v;
  v.f = f;
  unsigned u = v.u;
  return (ushort)((u + 0x7fffu + ((u >> 16) & 1u)) >> 16);  // RNE
}

// ---------------------------------------------------------------------------
// Graph setup: CSR by dst (counting sort), mean edge_attr for self loops
// ---------------------------------------------------------------------------

__global__ void count_deg_kernel(const int* __restrict__ dst, int* __restrict__ cnt) {
  int e = blockIdx.x * blockDim.x + threadIdx.x;
  if (e < EE) atomicAdd(&cnt[dst[e]], 1);
}

__global__ void scan_kernel(const int* __restrict__ cnt, int* __restrict__ off,
                            int* __restrict__ cursor) {
  __shared__ int wsum[16];
  __shared__ int carry_s;
  const int tid = threadIdx.x, lane = tid & 63, w = tid >> 6;
  if (tid == 0) carry_s = 0;
  __syncthreads();
  for (int base = 0; base < NN; base += 1024) {
    int i = base + tid;
    int v = (i < NN) ? (cnt[i] + 1) : 0;
    int x = v;
#pragma unroll
    for (int s = 1; s < 64; s <<= 1) {
      int t = __shfl_up(x, s);
      if (lane >= s) x += t;
    }
    if (lane == 63) wsum[w] = x;
    __syncthreads();
    if (w == 0) {
      int ws = (lane < 16) ? wsum[lane] : 0;
#pragma unroll
      for (int s = 1; s < 16; s <<= 1) {
        int t = __shfl_up(ws, s);
        if (lane >= s) ws += t;
      }
      if (lane < 16) wsum[lane] = ws;
    }
    __syncthreads();
    int wbase = (w == 0) ? 0 : wsum[w - 1];
    int total = wsum[15];
    int excl = carry_s + wbase + x - v;
    if (i < NN) { off[i] = excl; cursor[i] = excl; }
    __syncthreads();
    if (tid == 0) carry_s += total;
    __syncthreads();
  }
  if (threadIdx.x == 0) off[NN] = carry_s;
}

__global__ void scatter_kernel(const int* __restrict__ src, const int* __restrict__ dst,
                               int* __restrict__ cursor, int* __restrict__ csr_src,
                               int* __restrict__ csr_eid) {
  int e = blockIdx.x * blockDim.x + threadIdx.x;
  if (e >= EF) return;
  int s, d;
  if (e < EE) { s = src[e]; d = dst[e]; } else { s = e - EE; d = s; }
  int pos = atomicAdd(&cursor[d], 1);
  csr_src[pos] = s;
  csr_eid[pos] = e;
}

__global__ void mean_ea_kernel(const int* __restrict__ off, const int* __restrict__ csr_eid,
                               const int* __restrict__ cnt, const float* __restrict__ edge_attr,
                               float* __restrict__ mean_ea) {
  int t = blockIdx.x * blockDim.x + threadIdx.x;
  if (t >= NN * EDIM) return;
  int n = t / EDIM, d = t % EDIM;
  int s = off[n], e = off[n + 1];
  float sum = 0.f;
  for (int j = s; j < e; ++j) {
    int eid = csr_eid[j];
    if (eid < EE) sum += edge_attr[(size_t)eid * EDIM + d];
  }
  mean_ea[t] = sum / fmaxf((float)cnt[n], 1.f);
}

// ---------------------------------------------------------------------------
// dtype conversions
// ---------------------------------------------------------------------------

__global__ void cvt_x_kernel(const float* __restrict__ x, ushort* __restrict__ ab) {
  int t = blockIdx.x * blockDim.x + threadIdx.x;
  if (t >= NN * 32) return;
  int n = t >> 5, c = t & 31;
  ab[t] = (c < 16) ? f2b(x[n * 16 + c]) : (ushort)0;
}

__global__ void cvt_w_kernel(const float* __restrict__ W, ushort* __restrict__ Wt,
                             int K, int Kp, int HC) {
  int t = blockIdx.x * blockDim.x + threadIdx.x;
  if (t >= HC * Kp) return;
  int nc = t / Kp, k = t % Kp;
  Wt[t] = (k < K) ? f2b(W[(size_t)k * HC + nc]) : (ushort)0;
}

// ---------------------------------------------------------------------------
// bf16 MFMA GEMM (round-2 proven shape): wave = 16 rows x 64 cols, NFRAG=4.
// ---------------------------------------------------------------------------
__global__ __launch_bounds__(256) void mfma_gemm_kernel(
    const ushort* __restrict__ A, const ushort* __restrict__ Bt,
    ushort* __restrict__ C, int M, int K, int Nc) {
  const int lane = threadIdx.x & 63;
  const int wid = threadIdx.x >> 6;
  const int bm = blockIdx.y * 64 + wid * 16;
  const int bn = blockIdx.x * 64;
  const int r = lane & 15;
  const int kg = lane >> 4;

  f32x4 acc[4] = {};
  const int arow = bm + r;
  const bool aval = arow < M;
  const ushort* aptr = A + (size_t)arow * K + kg * 8;
  const ushort* bptr = Bt + (size_t)(bn + r) * K + kg * 8;

  for (int k0 = 0; k0 < K; k0 += 32) {
    bf16x8 af = {};
    if (aval) af = *(const bf16x8*)(aptr + k0);
#pragma unroll
    for (int nf = 0; nf < 4; ++nf) {
      bf16x8 bfr = *(const bf16x8*)(bptr + (size_t)nf * 16 * K + k0);
      acc[nf] = __builtin_amdgcn_mfma_f32_16x16x32_bf16(af, bfr, acc[nf], 0, 0, 0);
    }
  }
#pragma unroll
  for (int nf = 0; nf < 4; ++nf) {
#pragma unroll
    for (int reg = 0; reg < 4; ++reg) {
      int row = bm + kg * 4 + reg;
      if (row < M) C[(size_t)row * Nc + bn + nf * 16 + r] = f2b(acc[nf][reg]);
    }
  }
}

// ---------------------------------------------------------------------------
// a_s / a_d from bf16 h
// ---------------------------------------------------------------------------
__global__ void asd_kernel(const ushort* __restrict__ h, const float* __restrict__ atts,
                           const float* __restrict__ attd, float* __restrict__ a_s,
                           float* __restrict__ a_d, int H, int C) {
  int t = blockIdx.x * blockDim.x + threadIdx.x;
  if (t >= NN * H) return;
  int n = t / H, hh = t % H;
  const ushort* row = h + (size_t)n * H * C + (size_t)hh * C;
  float s = 0.f, d = 0.f;
  for (int c = 0; c < C; c += 2) {
    unsigned u = *(const unsigned*)(row + c);
    float v0 = b2f((ushort)(u & 0xffff));
    float v1 = b2f((ushort)(u >> 16));
    s += v0 * atts[hh * C + c] + v1 * atts[hh * C + c + 1];
    d += v0 * attd[hh * C + c] + v1 * attd[hh * C + c + 1];
  }
  a_s[t] = s;
  a_d[t] = d;
}

__global__ void wecomb_kernel(const float* __restrict__ We, const float* __restrict__ atte,
                              float* __restrict__ wec, int H, int C) {
  int t = blockIdx.x * blockDim.x + threadIdx.x;
  if (t >= EDIM * H) return;
  int d = t / H, hh = t % H;
  float v = 0.f;
  for (int c = 0; c < C; ++c) v += We[(size_t)d * H * C + hh * C + c] * atte[hh * C + c];
  wec[t] = v;
}

// a_se[j,h] = a_e(edge j) + a_s[src(j),h], in CSR order
__global__ void ase_kernel(const int* __restrict__ csr_eid, const int* __restrict__ csr_src,
                           const float* __restrict__ edge_attr, const float* __restrict__ mean_ea,
                           const float* __restrict__ wec, const float* __restrict__ a_s,
                           float* __restrict__ a_se, int H) {
  int t = blockIdx.x * blockDim.x + threadIdx.x;
  if (t >= EF * H) return;
  int j = t / H, hh = t % H;
  int eid = csr_eid[j];
  const float* ea = (eid < EE) ? &edge_attr[(size_t)eid * EDIM]
                               : &mean_ea[(size_t)(eid - EE) * EDIM];
  float v = 0.f;
#pragma unroll
  for (int d = 0; d < EDIM; ++d) v += ea[d] * wec[d * H + hh];
  a_se[t] = v + a_s[csr_src[j] * H + hh];
}

// ---------------------------------------------------------------------------
// Per-node softmax stats + edge weights: one wave per node.
// ---------------------------------------------------------------------------
template <int H>
__global__ __launch_bounds__(256) void statsw_kernel(
    const float* __restrict__ a_se, const float* __restrict__ a_d,
    const int* __restrict__ off, float* __restrict__ w) {
  const int n = (int)((blockIdx.x * blockDim.x + threadIdx.x) >> 6);
  const int lane = threadIdx.x & 63;
  if (n >= NN) return;
  const int start = off[n], end = off[n + 1];

  float adh[H];
#pragma unroll
  for (int h = 0; h < H; ++h) adh[h] = a_d[n * H + h];

  float mx[H];
#pragma unroll
  for (int h = 0; h < H; ++h) mx[h] = -1e30f;
  for (int j = start + lane; j < end; j += 64) {
    const float4* ap = (const float4*)(a_se + (size_t)j * H);
#pragma unroll
    for (int q = 0; q < H / 4; ++q) {
      float4 v = ap[q];
      float vv[4] = {v.x, v.y, v.z, v.w};
#pragma unroll
      for (int e = 0; e < 4; ++e) {
        int h = q * 4 + e;
        float al = vv[e] + adh[h];
        al = al > 0.f ? al : 0.2f * al;
        mx[h] = fmaxf(mx[h], al);
      }
    }
  }
#pragma unroll
  for (int s = 32; s > 0; s >>= 1)
#pragma unroll
    for (int h = 0; h < H; ++h) mx[h] = fmaxf(mx[h], __shfl_xor(mx[h], s));

  float sm[H];
#pragma unroll
  for (int h = 0; h < H; ++h) sm[h] = 0.f;
  for (int j = start + lane; j < end; j += 64) {
    const float4* ap = (const float4*)(a_se + (size_t)j * H);
#pragma unroll
    for (int q = 0; q < H / 4; ++q) {
      float4 v = ap[q];
      float vv[4] = {v.x, v.y, v.z, v.w};
#pragma unroll
      for (int e = 0; e < 4; ++e) {
        int h = q * 4 + e;
        float al = vv[e] + adh[h];
        al = al > 0.f ? al : 0.2f * al;
        sm[h] += __expf(al - mx[h]);
      }
    }
  }
#pragma unroll
  for (int s = 32; s > 0; s >>= 1)
#pragma unroll
    for (int h = 0; h < H; ++h) sm[h] += __shfl_xor(sm[h], s);
  float rd[H];
#pragma unroll
  for (int h = 0; h < H; ++h) rd[h] = 1.f / sm[h];

  for (int j = start + lane; j < end; j += 64) {
    const float4* ap = (const float4*)(a_se + (size_t)j * H);
    float* wp = w + (size_t)j * H;
#pragma unroll
    for (int q = 0; q < H / 4; ++q) {
      float4 v = ap[q];
      float vv[4] = {v.x, v.y, v.z, v.w};
      float ww[4];
#pragma unroll
      for (int e = 0; e < 4; ++e) {
        int h = q * 4 + e;
        float al = vv[e] + adh[h];
        al = al > 0.f ? al : 0.2f * al;
        ww[e] = __expf(al - mx[h]) * rd[h];
      }
      *(float4*)(wp + q * 4) = make_float4(ww[0], ww[1], ww[2], ww[3]);
    }
  }
}

// ---------------------------------------------------------------------------
// Gather with XCD-pinned feature chunks. Block -> XCD x = blockIdx%8
// (round-robin heuristic); chunk ch derived from x so each chunk's slice of
// hbuf is only pulled into the L2s of its 2-4 XCDs (compulsory FETCH drops
// NCH-fold). Coverage of (n,ch) is by rank enumeration -> correctness does
// not depend on the mapping. Wave = one node; lane owns FPL features.
// ---------------------------------------------------------------------------
template <int H, int C, int NCH>
__global__ __launch_bounds__(256) void gather_kernel(
    const float* __restrict__ w, const ushort* __restrict__ hb,
    const int* __restrict__ off, const int* __restrict__ csr_src,
    const float* __restrict__ bias, ushort* __restrict__ xb) {
  constexpr int HC = H * C;
  constexpr int CHUNK = HC / NCH;
  constexpr int FPL = CHUNK / 64;
  const int b = blockIdx.x;
  const int x = b & 7;
  int ch, rank;
  if (NCH == 3) {
    ch = (x * 3) >> 3;                        // 0,0,0,1,1,1,2,2
    const int base = ch * 3;                  // 0,3,6 (ch==2 -> 6)
    const int per = (ch == 2) ? 2 : 3;
    rank = (b >> 3) * per + (x - base);
  } else if (NCH == 2) {
    ch = x >> 2;
    rank = (b >> 3) * 4 + (x & 3);
  } else {
    ch = 0;
    rank = b;
  }
  const int wv = threadIdx.x >> 6;
  const int lane = threadIdx.x & 63;
  const int n = rank * 4 + wv;
  if (n >= NN) return;
  const int start = off[n], end = off[n + 1];
  const int fbase = ch * CHUNK + lane * FPL;
  const int head = fbase / C;

  float acc[FPL] = {};
  for (int j = start; j < end; ++j) {
    int srcn = csr_src[j];
    float wg = w[(size_t)j * H + head];
    const ushort* hp = hb + (size_t)srcn * HC + fbase;
    if (FPL == 4) {
      uint2 u = *(const uint2*)hp;
      acc[0] += wg * b2f((ushort)(u.x & 0xffff));
      acc[1] += wg * b2f((ushort)(u.x >> 16));
      acc[2 % FPL] += wg * b2f((ushort)(u.y & 0xffff));
      acc[3 % FPL] += wg * b2f((ushort)(u.y >> 16));
    } else {
      unsigned u = *(const unsigned*)hp;
      acc[0] += wg * b2f((ushort)(u & 0xffff));
      acc[1 % FPL] += wg * b2f((ushort)(u >> 16));
    }
  }
  ushort o[FPL];
#pragma unroll
  for (int i = 0; i < FPL; ++i) o[i] = f2b(fmaxf(acc[i] + bias[fbase + i], 0.f));
  if (FPL == 4) {
    uint2 pk;
    pk.x = (unsigned)o[0] | ((unsigned)o[1 % FPL] << 16);
    pk.y = (unsigned)o[2 % FPL] | ((unsigned)o[3 % FPL] << 16);
    *(uint2*)(xb + (size_t)n * HC + fbase) = pk;
  } else {
    unsigned pk = (unsigned)o[0] | ((unsigned)o[1 % FPL] << 16);
    *(unsigned*)(xb + (size_t)n * HC + fbase) = pk;
  }
}

// ---------------------------------------------------------------------------
// Final head: sigmoid(concat(x1,x2,x3) @ Wf + bf), bf16 inputs. 1 wave/node.
// ---------------------------------------------------------------------------
__global__ void final_kernel(const ushort* __restrict__ x1b, const ushort* __restrict__ x2b,
                             const ushort* __restrict__ x3b, const float* __restrict__ Wf,
                             const float* __restrict__ bf, float* __restrict__ out) {
  const int wave = (int)((blockIdx.x * blockDim.x + threadIdx.x) >> 6);
  const int lane = threadIdx.x & 63;
  if (wave >= NN) return;
  float acc = 0.f;
#pragma unroll
  for (int q = 0; q < 5; ++q) {
    int f0 = (q * 64 + lane) * 4;
    const ushort* sp;
    if (f0 < 256)      sp = x1b + (size_t)wave * 256 + f0;
    else if (f0 < 512) sp = x2b + (size_t)wave * 256 + (f0 - 256);
    else               sp = x3b + (size_t)wave * 768 + (f0 - 512);
    uint2 u = *(const uint2*)sp;
    float4 wv = *(const float4*)(Wf + f0);
    acc += b2f((ushort)(u.x & 0xffff)) * wv.x + b2f((ushort)(u.x >> 16)) * wv.y +
           b2f((ushort)(u.y & 0xffff)) * wv.z + b2f((ushort)(u.y >> 16)) * wv.w;
  }
#pragma unroll
  for (int s = 32; s > 0; s >>= 1) acc += __shfl_xor(acc, s);
  if (lane == 0) out[wave] = 1.f / (1.f + __expf(-(acc + bf[0])));
}

// ---------------------------------------------------------------------------

extern "C" void kernel_launch(void* const* d_in, const int* in_sizes, int n_in,
                              void* d_out, int out_size, void* d_ws, size_t ws_size,
                              hipStream_t stream) {
  const float* x     = (const float*)d_in[0];
  const int*   eidx  = (const int*)d_in[1];
  const float* eattr = (const float*)d_in[2];
  const float* W[3]   = {(const float*)d_in[3],  (const float*)d_in[9],  (const float*)d_in[15]};
  const float* ats[3] = {(const float*)d_in[4],  (const float*)d_in[10], (const float*)d_in[16]};
  const float* atd[3] = {(const float*)d_in[5],  (const float*)d_in[11], (const float*)d_in[17]};
  const float* We[3]  = {(const float*)d_in[6],  (const float*)d_in[12], (const float*)d_in[18]};
  const float* ate[3] = {(const float*)d_in[7],  (const float*)d_in[13], (const float*)d_in[19]};
  const float* bb[3]  = {(const float*)d_in[8],  (const float*)d_in[14], (const float*)d_in[20]};
  const float* Wf = (const float*)d_in[21];
  const float* bf = (const float*)d_in[22];
  float* out = (float*)d_out;

  const int* src = eidx;
  const int* dst = eidx + EE;

  char* p = (char*)d_ws;
  auto carve = [&](size_t bytes) -> char* {
    char* q = p;
    p += (bytes + 255) & ~(size_t)255;
    return q;
  };
  ushort* x1b   = (ushort*)carve((size_t)NN * 256 * 2);
  ushort* x2b   = (ushort*)carve((size_t)NN * 256 * 2);
  ushort* x3b   = (ushort*)carve((size_t)NN * 768 * 2);
  ushort* hbuf  = (ushort*)carve((size_t)NN * 768 * 2);
  ushort* abf1  = (ushort*)carve((size_t)NN * 32 * 2);
  ushort* wt1   = (ushort*)carve((size_t)256 * 32 * 2);
  ushort* wt2   = (ushort*)carve((size_t)256 * 256 * 2);
  ushort* wt3   = (ushort*)carve((size_t)768 * 256 * 2);
  float*  a_s   = (float*)carve((size_t)NN * 12 * 4);
  float*  a_d   = (float*)carve((size_t)NN * 12 * 4);
  float*  a_se  = (float*)carve((size_t)EF * 12 * 4);
  float*  wbuf  = (float*)carve((size_t)EF * 12 * 4);
  float*  mea   = (float*)carve((size_t)NN * EDIM * 4);
  float*  wec   = (float*)carve((size_t)EDIM * 12 * 4);
  int* cnt      = (int*)carve((size_t)NN * 4);
  int* off      = (int*)carve((size_t)(NN + 1) * 4);
  int* cursor   = (int*)carve((size_t)NN * 4);
  int* csr_src  = (int*)carve((size_t)EF * 4);
  int* csr_eid  = (int*)carve((size_t)EF * 4);

  // ---- graph structure ----
  hipMemsetAsync(cnt, 0, (size_t)NN * 4, stream);
  count_deg_kernel<<<(EE + 255) / 256, 256, 0, stream>>>(dst, cnt);
  scan_kernel<<<1, 1024, 0, stream>>>(cnt, off, cursor);
  scatter_kernel<<<(EF + 255) / 256, 256, 0, stream>>>(src, dst, cursor, csr_src, csr_eid);
  mean_ea_kernel<<<(NN * EDIM + 255) / 256, 256, 0, stream>>>(off, csr_eid, cnt, eattr, mea);

  // ---- dtype prep ----
  cvt_x_kernel<<<(NN * 32 + 255) / 256, 256, 0, stream>>>(x, abf1);
  cvt_w_kernel<<<(256 * 32 + 255) / 256, 256, 0, stream>>>(W[0], wt1, 16, 32, 256);
  cvt_w_kernel<<<(256 * 256 + 255) / 256, 256, 0, stream>>>(W[1], wt2, 256, 256, 256);
  cvt_w_kernel<<<(768 * 256 + 255) / 256, 256, 0, stream>>>(W[2], wt3, 256, 256, 768);

  const int Hs[3] = {8, 8, 12};
  const int Cs[3] = {32, 32, 64};
  const int Kp[3] = {32, 256, 256};
  const ushort* Ain[3] = {abf1, x1b, x2b};
  const ushort* Wt[3] = {wt1, wt2, wt3};
  ushort* xoutb[3] = {x1b, x2b, x3b};

  for (int L = 0; L < 3; ++L) {
    const int H = Hs[L], C = Cs[L], HC = H * C;
    // h = A @ Wt^T (bf16 MFMA), round-2 proven grid
    dim3 g(HC / 64, (NN + 63) / 64);
    mfma_gemm_kernel<<<g, 256, 0, stream>>>(Ain[L], Wt[L], hbuf, NN, Kp[L], HC);
    // attention scalars
    asd_kernel<<<(NN * H + 255) / 256, 256, 0, stream>>>(hbuf, ats[L], atd[L], a_s, a_d, H, C);
    wecomb_kernel<<<(EDIM * H + 255) / 256, 256, 0, stream>>>(We[L], ate[L], wec, H, C);
    ase_kernel<<<(EF * H + 255) / 256, 256, 0, stream>>>(csr_eid, csr_src, eattr, mea, wec,
                                                         a_s, a_se, H);
    // softmax weights
    int sblocks = (NN * 64 + 255) / 256;
    if (H == 8)
      statsw_kernel<8><<<sblocks, 256, 0, stream>>>(a_se, a_d, off, wbuf);
    else
      statsw_kernel<12><<<sblocks, 256, 0, stream>>>(a_se, a_d, off, wbuf);
    // gather (XCD-pinned chunks): NCH=2 for HC=256 (needs 10000 blocks),
    // NCH=3 for HC=768 (needs 20000 blocks)
    if (H == 8)
      gather_kernel<8, 32, 2><<<10000, 256, 0, stream>>>(wbuf, hbuf, off, csr_src,
                                                         bb[L], xoutb[L]);
    else
      gather_kernel<12, 64, 3><<<20000, 256, 0, stream>>>(wbuf, hbuf, off, csr_src,
                                                          bb[L], xoutb[L]);
  }

  final_kernel<<<(NN * 64 + 255) / 256, 256, 0, stream>>>(x1b, x2b, x3b, Wf, bf, out);
}

// Round 5
// 529.406 us; speedup vs baseline: 1.3835x; 1.3835x over previous
//
#include <hip/hip_runtime.h>

#define NN 20000
#define EE 320000
#define EF 340000   /* EE + NN self loops */
#define EDIM 22

typedef short bf16x8 __attribute__((ext_vector_type(8)));
typedef float f32x4 __attribute__((ext_vector_type(4)));

__device__ __forceinline__ float b2f(ushort u) {
  union { unsigned u; float f; } v;
  v.u = ((unsigned)u) << 16;
  return v.f;
}
__device__ __forceinline__ ushort f2b(float f) {
  union { float f; unsigned u; } v;
  v.f = f;
  unsigned u = v.u;
  return (ushort)((u + 0x7fffu + ((u >> 16) & 1u)) >> 16);  // RNE
}
__device__ __forceinline__ float lrelu(float a) { return a > 0.f ? a : 0.2f * a; }

// ---------------------------------------------------------------------------
// Graph setup: CSR by dst (counting sort), mean edge_attr for self loops
// ---------------------------------------------------------------------------

__global__ void count_deg_kernel(const int* __restrict__ dst, int* __restrict__ cnt) {
  int e = blockIdx.x * blockDim.x + threadIdx.x;
  if (e < EE) atomicAdd(&cnt[dst[e]], 1);
}

__global__ void scan_kernel(const int* __restrict__ cnt, int* __restrict__ off,
                            int* __restrict__ cursor) {
  __shared__ int wsum[16];
  __shared__ int carry_s;
  const int tid = threadIdx.x, lane = tid & 63, w = tid >> 6;
  if (tid == 0) carry_s = 0;
  __syncthreads();
  for (int base = 0; base < NN; base += 1024) {
    int i = base + tid;
    int v = (i < NN) ? (cnt[i] + 1) : 0;
    int x = v;
#pragma unroll
    for (int s = 1; s < 64; s <<= 1) {
      int t = __shfl_up(x, s);
      if (lane >= s) x += t;
    }
    if (lane == 63) wsum[w] = x;
    __syncthreads();
    if (w == 0) {
      int ws = (lane < 16) ? wsum[lane] : 0;
#pragma unroll
      for (int s = 1; s < 16; s <<= 1) {
        int t = __shfl_up(ws, s);
        if (lane >= s) ws += t;
      }
      if (lane < 16) wsum[lane] = ws;
    }
    __syncthreads();
    int wbase = (w == 0) ? 0 : wsum[w - 1];
    int total = wsum[15];
    int excl = carry_s + wbase + x - v;
    if (i < NN) { off[i] = excl; cursor[i] = excl; }
    __syncthreads();
    if (tid == 0) carry_s += total;
    __syncthreads();
  }
  if (threadIdx.x == 0) off[NN] = carry_s;
}

__global__ void scatter_kernel(const int* __restrict__ src, const int* __restrict__ dst,
                               int* __restrict__ cursor, int* __restrict__ csr_src,
                               int* __restrict__ csr_eid) {
  int e = blockIdx.x * blockDim.x + threadIdx.x;
  if (e >= EF) return;
  int s, d;
  if (e < EE) { s = src[e]; d = dst[e]; } else { s = e - EE; d = s; }
  int pos = atomicAdd(&cursor[d], 1);
  csr_src[pos] = s;
  csr_eid[pos] = e;
}

__global__ void mean_ea_kernel(const int* __restrict__ off, const int* __restrict__ csr_eid,
                               const int* __restrict__ cnt, const float* __restrict__ edge_attr,
                               float* __restrict__ mean_ea) {
  int t = blockIdx.x * blockDim.x + threadIdx.x;
  if (t >= NN * EDIM) return;
  int n = t / EDIM, d = t % EDIM;
  int s = off[n], e = off[n + 1];
  float sum = 0.f;
  for (int j = s; j < e; ++j) {
    int eid = csr_eid[j];
    if (eid < EE) sum += edge_attr[(size_t)eid * EDIM + d];
  }
  mean_ea[t] = sum / fmaxf((float)cnt[n], 1.f);
}

// ---------------------------------------------------------------------------
// dtype conversions
// ---------------------------------------------------------------------------

__global__ void cvt_x_kernel(const float* __restrict__ x, ushort* __restrict__ ab) {
  int t = blockIdx.x * blockDim.x + threadIdx.x;
  if (t >= NN * 32) return;
  int n = t >> 5, c = t & 31;
  ab[t] = (c < 16) ? f2b(x[n * 16 + c]) : (ushort)0;
}

__global__ void cvt_w_kernel(const float* __restrict__ W, ushort* __restrict__ Wt,
                             int K, int Kp, int HC) {
  int t = blockIdx.x * blockDim.x + threadIdx.x;
  if (t >= HC * Kp) return;
  int nc = t / Kp, k = t % Kp;
  Wt[t] = (k < K) ? f2b(W[(size_t)k * HC + nc]) : (ushort)0;
}

// ---------------------------------------------------------------------------
// bf16 MFMA GEMM (round-2 proven shape): wave = 16 rows x 64 cols, NFRAG=4.
// ---------------------------------------------------------------------------
__global__ __launch_bounds__(256) void mfma_gemm_kernel(
    const ushort* __restrict__ A, const ushort* __restrict__ Bt,
    ushort* __restrict__ C, int M, int K, int Nc) {
  const int lane = threadIdx.x & 63;
  const int wid = threadIdx.x >> 6;
  const int bm = blockIdx.y * 64 + wid * 16;
  const int bn = blockIdx.x * 64;
  const int r = lane & 15;
  const int kg = lane >> 4;

  f32x4 acc[4] = {};
  const int arow = bm + r;
  const bool aval = arow < M;
  const ushort* aptr = A + (size_t)arow * K + kg * 8;
  const ushort* bptr = Bt + (size_t)(bn + r) * K + kg * 8;

  for (int k0 = 0; k0 < K; k0 += 32) {
    bf16x8 af = {};
    if (aval) af = *(const bf16x8*)(aptr + k0);
#pragma unroll
    for (int nf = 0; nf < 4; ++nf) {
      bf16x8 bfr = *(const bf16x8*)(bptr + (size_t)nf * 16 * K + k0);
      acc[nf] = __builtin_amdgcn_mfma_f32_16x16x32_bf16(af, bfr, acc[nf], 0, 0, 0);
    }
  }
#pragma unroll
  for (int nf = 0; nf < 4; ++nf) {
#pragma unroll
    for (int reg = 0; reg < 4; ++reg) {
      int row = bm + kg * 4 + reg;
      if (row < M) C[(size_t)row * Nc + bn + nf * 16 + r] = f2b(acc[nf][reg]);
    }
  }
}

// ---------------------------------------------------------------------------
// a_s / a_d from bf16 h
// ---------------------------------------------------------------------------
__global__ void asd_kernel(const ushort* __restrict__ h, const float* __restrict__ atts,
                           const float* __restrict__ attd, float* __restrict__ a_s,
                           float* __restrict__ a_d, int H, int C) {
  int t = blockIdx.x * blockDim.x + threadIdx.x;
  if (t >= NN * H) return;
  int n = t / H, hh = t % H;
  const ushort* row = h + (size_t)n * H * C + (size_t)hh * C;
  float s = 0.f, d = 0.f;
  for (int c = 0; c < C; c += 2) {
    unsigned u = *(const unsigned*)(row + c);
    float v0 = b2f((ushort)(u & 0xffff));
    float v1 = b2f((ushort)(u >> 16));
    s += v0 * atts[hh * C + c] + v1 * atts[hh * C + c + 1];
    d += v0 * attd[hh * C + c] + v1 * attd[hh * C + c + 1];
  }
  a_s[t] = s;
  a_d[t] = d;
}

__global__ void wecomb_kernel(const float* __restrict__ We, const float* __restrict__ atte,
                              float* __restrict__ wec, int H, int C) {
  int t = blockIdx.x * blockDim.x + threadIdx.x;
  if (t >= EDIM * H) return;
  int d = t / H, hh = t % H;
  float v = 0.f;
  for (int c = 0; c < C; ++c) v += We[(size_t)d * H * C + hh * C + c] * atte[hh * C + c];
  wec[t] = v;
}

// a_se[j,h] = a_e(edge j) + a_s[src(j),h], in CSR order
__global__ void ase_kernel(const int* __restrict__ csr_eid, const int* __restrict__ csr_src,
                           const float* __restrict__ edge_attr, const float* __restrict__ mean_ea,
                           const float* __restrict__ wec, const float* __restrict__ a_s,
                           float* __restrict__ a_se, int H) {
  int t = blockIdx.x * blockDim.x + threadIdx.x;
  if (t >= EF * H) return;
  int j = t / H, hh = t % H;
  int eid = csr_eid[j];
  const float* ea = (eid < EE) ? &edge_attr[(size_t)eid * EDIM]
                               : &mean_ea[(size_t)(eid - EE) * EDIM];
  float v = 0.f;
#pragma unroll
  for (int d = 0; d < EDIM; ++d) v += ea[d] * wec[d * H + hh];
  a_se[t] = v + a_s[csr_src[j] * H + hh];
}

// ---------------------------------------------------------------------------
// Fused aggregation. Wave = (node, chunk of 256 features = HPC heads).
// Stats (segment max + denom) computed lane-parallel for the chunk's heads
// only; pass-2 gather is depth-4 software-pipelined: 4 independent
// csr_src/a_se/h-row loads in flight per iteration (latency-bound fix).
// ---------------------------------------------------------------------------
template <int H, int C, int NCH>
__global__ __launch_bounds__(256) void aggregate_kernel(
    const float* __restrict__ a_se, const float* __restrict__ a_d,
    const ushort* __restrict__ hb, const int* __restrict__ off,
    const int* __restrict__ csr_src, const float* __restrict__ bias,
    ushort* __restrict__ xb) {
  constexpr int HC = H * C;
  constexpr int CHUNK = HC / NCH;   // 256
  constexpr int HPC = H / NCH;      // heads per chunk
  constexpr int FPL = CHUNK / 64;   // 4 features per lane
  const int t = (int)((blockIdx.x * blockDim.x + threadIdx.x) >> 6);
  const int lane = threadIdx.x & 63;
  const int n = t / NCH, ch = t - n * NCH;
  if (n >= NN) return;
  const int start = off[n], end = off[n + 1];
  const int h0 = ch * HPC;

  float adh[HPC];
#pragma unroll
  for (int q = 0; q < HPC; ++q) adh[q] = a_d[n * H + h0 + q];

  // ---- pass 1a: segment max (lane-parallel over edges) ----
  float mx[HPC];
#pragma unroll
  for (int q = 0; q < HPC; ++q) mx[q] = -1e30f;
  for (int j = start + lane; j < end; j += 64) {
    const float* ap = a_se + (size_t)j * H + h0;
#pragma unroll
    for (int v = 0; v < HPC / 4; ++v) {
      float4 a4 = *(const float4*)(ap + v * 4);
      float av[4] = {a4.x, a4.y, a4.z, a4.w};
#pragma unroll
      for (int e = 0; e < 4; ++e) {
        int q = v * 4 + e;
        mx[q] = fmaxf(mx[q], lrelu(av[e] + adh[q]));
      }
    }
  }
#pragma unroll
  for (int s = 32; s > 0; s >>= 1)
#pragma unroll
    for (int q = 0; q < HPC; ++q) mx[q] = fmaxf(mx[q], __shfl_xor(mx[q], s));

  // ---- pass 1b: denominator ----
  float sm[HPC];
#pragma unroll
  for (int q = 0; q < HPC; ++q) sm[q] = 0.f;
  for (int j = start + lane; j < end; j += 64) {
    const float* ap = a_se + (size_t)j * H + h0;
#pragma unroll
    for (int v = 0; v < HPC / 4; ++v) {
      float4 a4 = *(const float4*)(ap + v * 4);
      float av[4] = {a4.x, a4.y, a4.z, a4.w};
#pragma unroll
      for (int e = 0; e < 4; ++e) {
        int q = v * 4 + e;
        sm[q] += __expf(lrelu(av[e] + adh[q]) - mx[q]);
      }
    }
  }
#pragma unroll
  for (int s = 32; s > 0; s >>= 1)
#pragma unroll
    for (int q = 0; q < HPC; ++q) sm[q] += __shfl_xor(sm[q], s);

  // ---- lane's head within chunk ----
  const int q = (lane * FPL) / C;
  const float my_ad = adh[q], my_mx = mx[q], my_rd = 1.f / sm[q];
  const int aoff = h0 + q;
  const int fbase = ch * CHUNK + lane * FPL;
  const ushort* hrow = hb + fbase;

  // ---- pass 2: depth-4 pipelined weighted gather ----
  float acc[FPL] = {};
  int j = start;
  for (; j + 4 <= end; j += 4) {
    int s0 = csr_src[j], s1 = csr_src[j + 1], s2 = csr_src[j + 2], s3 = csr_src[j + 3];
    float e0 = a_se[(size_t)j * H + aoff];
    float e1 = a_se[(size_t)(j + 1) * H + aoff];
    float e2 = a_se[(size_t)(j + 2) * H + aoff];
    float e3 = a_se[(size_t)(j + 3) * H + aoff];
    uint2 u0 = *(const uint2*)(hrow + (size_t)s0 * HC);
    uint2 u1 = *(const uint2*)(hrow + (size_t)s1 * HC);
    uint2 u2 = *(const uint2*)(hrow + (size_t)s2 * HC);
    uint2 u3 = *(const uint2*)(hrow + (size_t)s3 * HC);
    float w0 = __expf(lrelu(e0 + my_ad) - my_mx) * my_rd;
    float w1 = __expf(lrelu(e1 + my_ad) - my_mx) * my_rd;
    float w2 = __expf(lrelu(e2 + my_ad) - my_mx) * my_rd;
    float w3 = __expf(lrelu(e3 + my_ad) - my_mx) * my_rd;
    acc[0] += w0 * b2f((ushort)(u0.x & 0xffff)) + w1 * b2f((ushort)(u1.x & 0xffff)) +
              w2 * b2f((ushort)(u2.x & 0xffff)) + w3 * b2f((ushort)(u3.x & 0xffff));
    acc[1] += w0 * b2f((ushort)(u0.x >> 16)) + w1 * b2f((ushort)(u1.x >> 16)) +
              w2 * b2f((ushort)(u2.x >> 16)) + w3 * b2f((ushort)(u3.x >> 16));
    acc[2] += w0 * b2f((ushort)(u0.y & 0xffff)) + w1 * b2f((ushort)(u1.y & 0xffff)) +
              w2 * b2f((ushort)(u2.y & 0xffff)) + w3 * b2f((ushort)(u3.y & 0xffff));
    acc[3] += w0 * b2f((ushort)(u0.y >> 16)) + w1 * b2f((ushort)(u1.y >> 16)) +
              w2 * b2f((ushort)(u2.y >> 16)) + w3 * b2f((ushort)(u3.y >> 16));
  }
  for (; j < end; ++j) {
    int s0 = csr_src[j];
    float e0 = a_se[(size_t)j * H + aoff];
    uint2 u0 = *(const uint2*)(hrow + (size_t)s0 * HC);
    float w0 = __expf(lrelu(e0 + my_ad) - my_mx) * my_rd;
    acc[0] += w0 * b2f((ushort)(u0.x & 0xffff));
    acc[1] += w0 * b2f((ushort)(u0.x >> 16));
    acc[2] += w0 * b2f((ushort)(u0.y & 0xffff));
    acc[3] += w0 * b2f((ushort)(u0.y >> 16));
  }

  // ---- bias + relu + bf16 store ----
  ushort o[FPL];
#pragma unroll
  for (int i = 0; i < FPL; ++i) o[i] = f2b(fmaxf(acc[i] + bias[fbase + i], 0.f));
  uint2 pk;
  pk.x = (unsigned)o[0] | ((unsigned)o[1] << 16);
  pk.y = (unsigned)o[2] | ((unsigned)o[3] << 16);
  *(uint2*)(xb + (size_t)n * HC + fbase) = pk;
}

// ---------------------------------------------------------------------------
// Final head: sigmoid(concat(x1,x2,x3) @ Wf + bf), bf16 inputs. 1 wave/node.
// ---------------------------------------------------------------------------
__global__ void final_kernel(const ushort* __restrict__ x1b, const ushort* __restrict__ x2b,
                             const ushort* __restrict__ x3b, const float* __restrict__ Wf,
                             const float* __restrict__ bf, float* __restrict__ out) {
  const int wave = (int)((blockIdx.x * blockDim.x + threadIdx.x) >> 6);
  const int lane = threadIdx.x & 63;
  if (wave >= NN) return;
  float acc = 0.f;
#pragma unroll
  for (int q = 0; q < 5; ++q) {
    int f0 = (q * 64 + lane) * 4;
    const ushort* sp;
    if (f0 < 256)      sp = x1b + (size_t)wave * 256 + f0;
    else if (f0 < 512) sp = x2b + (size_t)wave * 256 + (f0 - 256);
    else               sp = x3b + (size_t)wave * 768 + (f0 - 512);
    uint2 u = *(const uint2*)sp;
    float4 wv = *(const float4*)(Wf + f0);
    acc += b2f((ushort)(u.x & 0xffff)) * wv.x + b2f((ushort)(u.x >> 16)) * wv.y +
           b2f((ushort)(u.y & 0xffff)) * wv.z + b2f((ushort)(u.y >> 16)) * wv.w;
  }
#pragma unroll
  for (int s = 32; s > 0; s >>= 1) acc += __shfl_xor(acc, s);
  if (lane == 0) out[wave] = 1.f / (1.f + __expf(-(acc + bf[0])));
}

// ---------------------------------------------------------------------------

extern "C" void kernel_launch(void* const* d_in, const int* in_sizes, int n_in,
                              void* d_out, int out_size, void* d_ws, size_t ws_size,
                              hipStream_t stream) {
  const float* x     = (const float*)d_in[0];
  const int*   eidx  = (const int*)d_in[1];
  const float* eattr = (const float*)d_in[2];
  const float* W[3]   = {(const float*)d_in[3],  (const float*)d_in[9],  (const float*)d_in[15]};
  const float* ats[3] = {(const float*)d_in[4],  (const float*)d_in[10], (const float*)d_in[16]};
  const float* atd[3] = {(const float*)d_in[5],  (const float*)d_in[11], (const float*)d_in[17]};
  const float* We[3]  = {(const float*)d_in[6],  (const float*)d_in[12], (const float*)d_in[18]};
  const float* ate[3] = {(const float*)d_in[7],  (const float*)d_in[13], (const float*)d_in[19]};
  const float* bb[3]  = {(const float*)d_in[8],  (const float*)d_in[14], (const float*)d_in[20]};
  const float* Wf = (const float*)d_in[21];
  const float* bf = (const float*)d_in[22];
  float* out = (float*)d_out;

  const int* src = eidx;
  const int* dst = eidx + EE;

  char* p = (char*)d_ws;
  auto carve = [&](size_t bytes) -> char* {
    char* q = p;
    p += (bytes + 255) & ~(size_t)255;
    return q;
  };
  ushort* x1b   = (ushort*)carve((size_t)NN * 256 * 2);
  ushort* x2b   = (ushort*)carve((size_t)NN * 256 * 2);
  ushort* x3b   = (ushort*)carve((size_t)NN * 768 * 2);
  ushort* hbuf  = (ushort*)carve((size_t)NN * 768 * 2);
  ushort* abf1  = (ushort*)carve((size_t)NN * 32 * 2);
  ushort* wt1   = (ushort*)carve((size_t)256 * 32 * 2);
  ushort* wt2   = (ushort*)carve((size_t)256 * 256 * 2);
  ushort* wt3   = (ushort*)carve((size_t)768 * 256 * 2);
  float*  a_s   = (float*)carve((size_t)NN * 12 * 4);
  float*  a_d   = (float*)carve((size_t)NN * 12 * 4);
  float*  a_se  = (float*)carve((size_t)EF * 12 * 4);
  float*  mea   = (float*)carve((size_t)NN * EDIM * 4);
  float*  wec   = (float*)carve((size_t)EDIM * 12 * 4);
  int* cnt      = (int*)carve((size_t)NN * 4);
  int* off      = (int*)carve((size_t)(NN + 1) * 4);
  int* cursor   = (int*)carve((size_t)NN * 4);
  int* csr_src  = (int*)carve((size_t)EF * 4);
  int* csr_eid  = (int*)carve((size_t)EF * 4);

  // ---- graph structure ----
  hipMemsetAsync(cnt, 0, (size_t)NN * 4, stream);
  count_deg_kernel<<<(EE + 255) / 256, 256, 0, stream>>>(dst, cnt);
  scan_kernel<<<1, 1024, 0, stream>>>(cnt, off, cursor);
  scatter_kernel<<<(EF + 255) / 256, 256, 0, stream>>>(src, dst, cursor, csr_src, csr_eid);
  mean_ea_kernel<<<(NN * EDIM + 255) / 256, 256, 0, stream>>>(off, csr_eid, cnt, eattr, mea);

  // ---- dtype prep ----
  cvt_x_kernel<<<(NN * 32 + 255) / 256, 256, 0, stream>>>(x, abf1);
  cvt_w_kernel<<<(256 * 32 + 255) / 256, 256, 0, stream>>>(W[0], wt1, 16, 32, 256);
  cvt_w_kernel<<<(256 * 256 + 255) / 256, 256, 0, stream>>>(W[1], wt2, 256, 256, 256);
  cvt_w_kernel<<<(768 * 256 + 255) / 256, 256, 0, stream>>>(W[2], wt3, 256, 256, 768);

  const int Hs[3] = {8, 8, 12};
  const int Cs[3] = {32, 32, 64};
  const int Kp[3] = {32, 256, 256};
  const ushort* Ain[3] = {abf1, x1b, x2b};
  const ushort* Wt[3] = {wt1, wt2, wt3};
  ushort* xoutb[3] = {x1b, x2b, x3b};

  for (int L = 0; L < 3; ++L) {
    const int H = Hs[L], C = Cs[L], HC = H * C;
    // h = A @ Wt^T (bf16 MFMA), round-2 proven grid
    dim3 g(HC / 64, (NN + 63) / 64);
    mfma_gemm_kernel<<<g, 256, 0, stream>>>(Ain[L], Wt[L], hbuf, NN, Kp[L], HC);
    // attention scalars
    asd_kernel<<<(NN * H + 255) / 256, 256, 0, stream>>>(hbuf, ats[L], atd[L], a_s, a_d, H, C);
    wecomb_kernel<<<(EDIM * H + 255) / 256, 256, 0, stream>>>(We[L], ate[L], wec, H, C);
    ase_kernel<<<(EF * H + 255) / 256, 256, 0, stream>>>(csr_eid, csr_src, eattr, mea, wec,
                                                         a_s, a_se, H);
    // fused softmax + pipelined gather
    if (H == 8) {
      int blocks = (NN * 1 * 64 + 255) / 256;
      aggregate_kernel<8, 32, 1><<<blocks, 256, 0, stream>>>(a_se, a_d, hbuf, off, csr_src,
                                                             bb[L], xoutb[L]);
    } else {
      int blocks = (NN * 3 * 64 + 255) / 256;
      aggregate_kernel<12, 64, 3><<<blocks, 256, 0, stream>>>(a_se, a_d, hbuf, off, csr_src,
                                                              bb[L], xoutb[L]);
    }
  }

  final_kernel<<<(NN * 64 + 255) / 256, 256, 0, stream>>>(x1b, x2b, x3b, Wf, bf, out);
}